// Round 2
// baseline (340.539 us; speedup 1.0000x reference)
//
#include <hip/hip_runtime.h>
#include <math.h>
#include <stdint.h>

#define VOCAB 50257
#define KD 5
#define NBATCH 256
#define NT 1024
#define NW (NT / 64)
#define NSLOT 13          /* ceil(nvec/NT); nvec in {12563,12564} */
#define NSEG (NSLOT + 2)  /* head seg + 13 slot segs + tail seg */

// One block per batch element. Lazy accept scan (E[rows scanned] ~= 1.0),
// with the scanned row's expf() values CACHED IN REGISTERS (13 float4 slots
// = 52 f32 VGPRs, statically indexed). Fallback sampling then needs no
// global re-read and no exp recompute: per-slot adjusted/raw sums come
// straight from registers. CDF partition = [head][slot0..12][tail] in vocab
// order (alignment-shifted segments), so slot<->register mapping is static.
__global__ __launch_bounds__(NT) void spec_decode_kernel(
    const int* __restrict__ dtok,     // [B,K] int32
    const float* __restrict__ dlp,    // [B,K] f32
    const float* __restrict__ logits, // [B,K,V] f32
    const float* __restrict__ rnd,    // [B,K] f32
    const float* __restrict__ usmp,   // [B] f32
    int* __restrict__ out)            // [B*K + B + B] int32
{
    const int b    = blockIdx.x;
    const int tid  = threadIdx.x;
    const int lane = tid & 63;
    const int wv   = tid >> 6;

    __shared__ double s_w[NW];
    __shared__ double s_pA[NSLOT][NW + 1]; // +1 pad: conflict-free phase-4 reads
    __shared__ double s_pR[NSLOT][NW + 1];
    __shared__ double s_ht[6];             // head exps [0..2], tail exps [3..5]
    __shared__ double s_db[2];
    __shared__ int    s_ib[2];
    __shared__ int    s_c[NW];

    float ef[NSLOT][4]; // register cache of expf(row) for the last scanned row

    // ---------------- Phase 1: lazy accept/reject scan ----------------
    double       Zsel  = 0.0;
    int          n_acc = KD;
    int          headS = 0, nvecS = 0;
    const float* rowS  = nullptr;

    for (int r = 0; r < KD; ++r) {
        const float* row = logits + ((size_t)b * KD + r) * (size_t)VOCAB;
        const int  head = (int)((4u - ((((uintptr_t)row) >> 2) & 3u)) & 3u);
        const int  nvec = (VOCAB - head) >> 2;
        const float4* row4 = (const float4*)(row + head);

        float tlogit = 0.f, dl = 0.f, rv = 0.f;
        if (tid == 0) {
            int tok = dtok[b * KD + r];
            tlogit  = row[tok];
            dl      = dlp[b * KD + r];
            rv      = rnd[b * KD + r];
        }

        double l0 = 0.0, l1 = 0.0;
        if (tid < head) {
            double eh = (double)expf(row[tid]);
            l0 += eh;
            s_ht[tid] = eh;
        }
        #pragma unroll
        for (int c = 0; c < NSLOT - 1; ++c) { // slots 0..11 always full
            float4 x = row4[c * NT + tid];
            float e0 = expf(x.x), e1 = expf(x.y), e2 = expf(x.z), e3 = expf(x.w);
            ef[c][0] = e0; ef[c][1] = e1; ef[c][2] = e2; ef[c][3] = e3;
            l0 += (double)e0 + (double)e1;
            l1 += (double)e2 + (double)e3;
        }
        { // partial slot 12
            int i = (NSLOT - 1) * NT + tid;
            if (i < nvec) {
                float4 x = row4[i];
                float e0 = expf(x.x), e1 = expf(x.y), e2 = expf(x.z), e3 = expf(x.w);
                ef[NSLOT - 1][0] = e0; ef[NSLOT - 1][1] = e1;
                ef[NSLOT - 1][2] = e2; ef[NSLOT - 1][3] = e3;
                l0 += (double)e0 + (double)e1;
                l1 += (double)e2 + (double)e3;
            }
        }
        const int tail_start = head + (nvec << 2);
        const int tail_cnt   = VOCAB - tail_start;
        if (tid < tail_cnt) {
            double et = (double)expf(row[tail_start + tid]);
            l1 += et;
            s_ht[3 + tid] = et;
        }

        double local = l0 + l1;
        for (int off = 32; off; off >>= 1) local += __shfl_down(local, off, 64);
        if (lane == 0) s_w[wv] = local;
        __syncthreads();
        if (wv == 0) {
            double v = (lane < NW) ? s_w[lane] : 0.0;
            for (int off = 8; off; off >>= 1) v += __shfl_down(v, off, 64);
            if (lane == 0) {
                double Z   = v;
                double tlp = (double)tlogit - log(Z);
                double ap  = exp(tlp - (double)dl);
                if (ap > 1.0) ap = 1.0;
                s_db[0] = Z;
                s_ib[0] = ((double)rv < ap) ? 1 : 0;
            }
        }
        __syncthreads();
        Zsel  = s_db[0];
        int acc = s_ib[0];
        headS = head; nvecS = nvec; rowS = row;
        // safe without extra sync: next row's s_db/s_ib writes happen only
        // after its first barrier, i.e. after every thread read them here.
        if (!acc) { n_acc = r; break; }
    }

    // ---------------- Phase 2: write accepted tokens / n ----------------
    if (tid == 0) {
        for (int r = 0; r < KD; ++r)
            out[b * KD + r] = (r < n_acc) ? dtok[b * KD + r] : 0;
        out[NBATCH * KD + b] = n_acc;
        if (n_acc >= KD) out[NBATCH * KD + NBATCH + b] = 0; // PAD, no resample
    }
    if (n_acc >= KD) return; // block-uniform

    const double invZ = 1.0 / Zsel;
    const double dp   = exp((double)dlp[b * KD + n_acc]);
    const int    head = headS;
    const int    nvec = nvecS;
    const float4* row4 = (const float4*)(rowS + head);

    // ---------------- Phase 3: per-slot sums from the register cache ------
    #pragma unroll
    for (int c = 0; c < NSLOT; ++c) {
        double aS = 0.0, rS = 0.0;
        bool v = (c < NSLOT - 1) || ((NSLOT - 1) * NT + tid < nvec);
        if (v) {
            #pragma unroll
            for (int e = 0; e < 4; ++e) {
                double p = (double)ef[c][e] * invZ;
                rS += p;
                double a = p - dp;
                if (a > 0.0) aS += a;
            }
        }
        for (int off = 32; off; off >>= 1) {
            aS += __shfl_down(aS, off, 64);
            rS += __shfl_down(rS, off, 64);
        }
        if (lane == 0) { s_pA[c][wv] = aS; s_pR[c][wv] = rS; }
    }
    __syncthreads();

    // ---------------- Phase 4: 15-segment CDF walk (wave 0) ---------------
    if (wv == 0) {
        double A = 0.0, R = 0.0;
        if (lane >= 1 && lane <= NSLOT) {
            #pragma unroll
            for (int w = 0; w < NW; ++w) { A += s_pA[lane - 1][w]; R += s_pR[lane - 1][w]; }
        } else if (lane == 0) {
            for (int j = 0; j < head; ++j) {
                double p = s_ht[j] * invZ;
                R += p;
                double a = p - dp; if (a > 0.0) A += a;
            }
        } else if (lane == NSEG - 1) {
            int tcnt = VOCAB - head - (nvec << 2);
            for (int j = 0; j < tcnt; ++j) {
                double p = s_ht[3 + j] * invZ;
                R += p;
                double a = p - dp; if (a > 0.0) A += a;
            }
        }
        double sa = A, sr = R; // inclusive scan over segment index == lane
        for (int off = 1; off < 16; off <<= 1) {
            double va = __shfl_up(sa, (unsigned)off, 64); if (lane >= off) sa += va;
            double vr = __shfl_up(sr, (unsigned)off, 64); if (lane >= off) sr += vr;
        }
        double SA     = __shfl(sa, NSEG - 1, 64); // total adjusted mass
        int    useAdj = (SA > 0.0) ? 1 : 0;
        double Tot    = useAdj ? SA : __shfl(sr, NSEG - 1, 64);
        double T      = (double)usmp[b] * Tot;
        double incl   = useAdj ? sa : sr;
        double val    = useAdj ? A  : R;
        bool crossed  = (lane < NSEG) && (incl >= T);
        unsigned long long mk = __ballot(crossed);
        int    cseg = mk ? (int)(__ffsll(mk) - 1) : (NSEG - 1);
        double Pex  = __shfl(incl, cseg, 64) - __shfl(val, cseg, 64);
        if (lane == 0) {
            s_db[0] = Pex; s_db[1] = T;
            s_ib[0] = cseg; s_ib[1] = useAdj;
        }
    }
    __syncthreads();

    const double P      = s_db[0];
    const double T      = s_db[1];
    const int    cseg   = s_ib[0];
    const int    useAdj = s_ib[1];

    // ---------------- Phase 5: in-segment scan -> sampled index -----------
    if (cseg >= 1 && cseg <= NSLOT) { // block-uniform branch
        const int  c     = cseg - 1;
        const int  i4    = c * NT + tid;
        const bool valid = i4 < nvec;
        double c0 = 0, c1 = 0, c2 = 0, c3 = 0, tsum = 0;
        if (valid) {
            float4 x = row4[i4]; // L2-hit; expf == cached value bit-exactly
            double p0 = (double)expf(x.x) * invZ;
            double p1 = (double)expf(x.y) * invZ;
            double p2 = (double)expf(x.z) * invZ;
            double p3 = (double)expf(x.w) * invZ;
            double g0 = useAdj ? fmax(p0 - dp, 0.0) : p0;
            double g1 = useAdj ? fmax(p1 - dp, 0.0) : p1;
            double g2 = useAdj ? fmax(p2 - dp, 0.0) : p2;
            double g3 = useAdj ? fmax(p3 - dp, 0.0) : p3;
            c0 = g0; c1 = c0 + g1; c2 = c1 + g2; c3 = c2 + g3;
            tsum = c3;
        }
        // wave inclusive scan of per-thread totals
        double sc = tsum;
        for (int off = 1; off < 64; off <<= 1) {
            double v = __shfl_up(sc, (unsigned)off, 64);
            if (lane >= off) sc += v;
        }
        if (lane == 63) s_w[wv] = sc;
        __syncthreads();
        double woff = 0.0;
        for (int w = 0; w < wv; ++w) woff += s_w[w];
        double base = P + woff + (sc - tsum); // exclusive prefix for this thread
        int bj = -1;
        if (valid) {
            if      (base + c0 >= T) bj = 0;
            else if (base + c1 >= T) bj = 1;
            else if (base + c2 >= T) bj = 2;
            else if (base + c3 >= T) bj = 3;
        }
        unsigned long long mk = __ballot(bj >= 0);
        int L  = mk ? (int)(__ffsll(mk) - 1) : 0;
        int jl = __shfl(bj, L, 64); // first crossing lane's element offset
        if (lane == 0)
            s_c[wv] = mk ? (head + 4 * (c * NT + wv * 64 + L) + jl) : 0x7FFFFFFF;
        __syncthreads();
        if (tid == 0) {
            int best = 0x7FFFFFFF;
            for (int w = 0; w < NW; ++w) best = min(best, s_c[w]);
            int smp;
            if (best == 0x7FFFFFFF) { // rounding guard: segment end
                int endv = c * NT + NT; if (endv > nvec) endv = nvec;
                smp = head + 4 * endv - 1;
            } else {
                smp = best;
            }
            out[NBATCH * KD + NBATCH + b] = smp;
        }
    } else if (tid == 0) { // head (cseg==0) or tail segment: <=3 elems, serial
        int smp = -1;
        if (cseg == 0) {
            double cum = P;
            for (int j = 0; j < head; ++j) {
                double p = s_ht[j] * invZ;
                double g = useAdj ? fmax(p - dp, 0.0) : p;
                cum += g;
                if (cum >= T) { smp = j; break; }
            }
            if (smp < 0) smp = (head > 0) ? head - 1 : 0;
        } else {
            int ts   = head + (nvec << 2);
            int tcnt = VOCAB - ts;
            double cum = P;
            for (int j = 0; j < tcnt; ++j) {
                double p = s_ht[3 + j] * invZ;
                double g = useAdj ? fmax(p - dp, 0.0) : p;
                cum += g;
                if (cum >= T) { smp = ts + j; break; }
            }
            if (smp < 0) smp = VOCAB - 1;
        }
        out[NBATCH * KD + NBATCH + b] = smp;
    }
}

extern "C" void kernel_launch(void* const* d_in, const int* in_sizes, int n_in,
                              void* d_out, int out_size, void* d_ws, size_t ws_size,
                              hipStream_t stream) {
    const int*   dtok   = (const int*)d_in[0];
    const float* dlp    = (const float*)d_in[1];
    const float* logits = (const float*)d_in[2];
    const float* rnd    = (const float*)d_in[3];
    const float* usmp   = (const float*)d_in[4];
    int*         out    = (int*)d_out;
    (void)in_sizes; (void)n_in; (void)out_size; (void)d_ws; (void)ws_size;
    spec_decode_kernel<<<dim3(NBATCH), dim3(NT), 0, stream>>>(
        dtok, dlp, logits, rnd, usmp, out);
}

// Round 3
// 321.047 us; speedup vs baseline: 1.0607x; 1.0607x over previous
//
#include <hip/hip_runtime.h>
#include <math.h>
#include <stdint.h>

#define VOCAB 50257
#define KD 5
#define NBATCH 256
#define NT 1024
#define NW (NT / 64)
#define NSLOT 13          /* ceil(nvec/NT); nvec in {12563,12564} */
#define NSEG (NSLOT + 2)  /* head seg + 13 slot segs + tail seg */

// One block per batch element. Lazy accept scan (E[rows scanned] ~= 1.0).
// Phase 1 produces, as by-products of the Z reduction: per-slot raw exp sums
// (s_pR) and the row max of expf (s_emax). Since S_adj>0 <=> emax*invZ>dp,
// the useAdj decision needs no second pass; ~87% of blocks skip phase 3
// (the 201KB re-read) entirely and sample straight from s_pR.
// No per-thread arrays (round-2 lesson: 52-VGPR row cache spilled to scratch).
__global__ __launch_bounds__(NT) void spec_decode_kernel(
    const int* __restrict__ dtok,     // [B,K] int32
    const float* __restrict__ dlp,    // [B,K] f32
    const float* __restrict__ logits, // [B,K,V] f32
    const float* __restrict__ rnd,    // [B,K] f32
    const float* __restrict__ usmp,   // [B] f32
    int* __restrict__ out)            // [B*K + B + B] int32
{
    const int b    = blockIdx.x;
    const int tid  = threadIdx.x;
    const int lane = tid & 63;
    const int wv   = tid >> 6;

    __shared__ double s_pR[NSLOT][NW + 1]; // raw exp sums (unscaled)
    __shared__ double s_pA[NSLOT][NW + 1]; // adjusted sums (scaled, clipped)
    __shared__ double s_ht[6];             // head exps [0..2], tail exps [3..5]
    __shared__ float  s_mx[NW];
    __shared__ float  s_emax;
    __shared__ double s_db[2];
    __shared__ int    s_ib[2];
    __shared__ double s_w[NW];

    // ---------------- Phase 1: lazy accept/reject scan ----------------
    double       Zsel  = 0.0;
    int          n_acc = KD;
    int          headS = 0, nvecS = 0;
    const float* rowS  = nullptr;

    for (int r = 0; r < KD; ++r) {
        const float* row = logits + ((size_t)b * KD + r) * (size_t)VOCAB;
        const int  head = (int)((4u - ((((uintptr_t)row) >> 2) & 3u)) & 3u);
        const int  nvec = (VOCAB - head) >> 2;
        const int  tail_start = head + (nvec << 2);
        const float4* row4 = (const float4*)(row + head);

        float tlogit = 0.f, dl = 0.f, rv = 0.f;
        if (tid == 0) {
            int tok = dtok[b * KD + r];
            tlogit  = row[tok];
            dl      = dlp[b * KD + r];
            rv      = rnd[b * KD + r];
        }

        float mx = 0.0f; // exps are all > 0
        if (tid < head) {
            float e = expf(row[tid]);
            s_ht[tid] = (double)e;
            mx = fmaxf(mx, e);
        }
        if (tid < VOCAB - tail_start) {
            float e = expf(row[tail_start + tid]);
            s_ht[3 + tid] = (double)e;
            mx = fmaxf(mx, e);
        }
        #pragma unroll
        for (int c = 0; c < NSLOT; ++c) {
            double sl = 0.0;
            const int i = c * NT + tid;
            if (c < NSLOT - 1 || i < nvec) { // slots 0..11 always full
                float4 x = row4[i];
                float e0 = expf(x.x), e1 = expf(x.y), e2 = expf(x.z), e3 = expf(x.w);
                mx = fmaxf(fmaxf(mx, fmaxf(e0, e1)), fmaxf(e2, e3));
                sl = ((double)e0 + (double)e1) + ((double)e2 + (double)e3);
            }
            for (int off = 32; off; off >>= 1) sl += __shfl_down(sl, off, 64);
            if (lane == 0) s_pR[c][wv] = sl;
        }
        for (int off = 32; off; off >>= 1) mx = fmaxf(mx, __shfl_down(mx, off, 64));
        if (lane == 0) s_mx[wv] = mx;
        __syncthreads();

        if (wv == 0) {
            // Z = sum(slot sums) + head + tail; 52 lanes gather 4 partials each
            double v = 0.0;
            if (lane < NSLOT * (NW / 4)) {
                int c = lane >> 2, w0 = (lane & 3) << 2;
                v = (s_pR[c][w0] + s_pR[c][w0 + 1]) + (s_pR[c][w0 + 2] + s_pR[c][w0 + 3]);
            } else if (lane == 52) {
                for (int j = 0; j < head; ++j) v += s_ht[j];
            } else if (lane == 53) {
                int tcnt = VOCAB - tail_start;
                for (int j = 0; j < tcnt; ++j) v += s_ht[3 + j];
            }
            for (int off = 32; off; off >>= 1) v += __shfl_down(v, off, 64);
            float m = (lane < NW) ? s_mx[lane] : 0.0f;
            for (int off = 8; off; off >>= 1) m = fmaxf(m, __shfl_down(m, off, 64));
            if (lane == 0) {
                double Z   = v;
                double tlp = (double)tlogit - log(Z);
                double ap  = exp(tlp - (double)dl);
                if (ap > 1.0) ap = 1.0;
                s_db[0] = Z;
                s_ib[0] = ((double)rv < ap) ? 1 : 0;
                s_emax  = m;
            }
        }
        __syncthreads();
        Zsel  = s_db[0];
        int acc = s_ib[0];
        headS = head; nvecS = nvec; rowS = row;
        // safe without extra sync: next row's s_db/s_ib/s_pR writes happen only
        // after its own barrier pair, i.e. after every thread read them here.
        if (!acc) { n_acc = r; break; }
    }

    // ---------------- Phase 2: write accepted tokens / n ----------------
    if (tid == 0) {
        for (int r = 0; r < KD; ++r)
            out[b * KD + r] = (r < n_acc) ? dtok[b * KD + r] : 0;
        out[NBATCH * KD + b] = n_acc;
        if (n_acc >= KD) out[NBATCH * KD + NBATCH + b] = 0; // PAD, no resample
    }
    if (n_acc >= KD) return; // block-uniform

    const double invZ = 1.0 / Zsel;
    const double dp   = exp((double)dlp[b * KD + n_acc]);
    const int    head = headS;
    const int    nvec = nvecS;
    const float4* row4 = (const float4*)(rowS + head);
    // S_adj > 0  <=>  max_i p_i > dp (f64 sums of nonnegatives are monotone)
    const int useAdj = ((double)s_emax * invZ > dp) ? 1 : 0;

    // ------- Phase 3 (adjusted blocks only, ~13%): per-slot clipped sums ---
    if (useAdj) {
        #pragma unroll
        for (int c = 0; c < NSLOT; ++c) {
            double aS = 0.0;
            const int i = c * NT + tid;
            if (c < NSLOT - 1 || i < nvec) {
                float4 x = row4[i]; // L2/LLC hit; expf bit-matches phase 1
                double p0 = (double)expf(x.x) * invZ;
                double p1 = (double)expf(x.y) * invZ;
                double p2 = (double)expf(x.z) * invZ;
                double p3 = (double)expf(x.w) * invZ;
                double a0 = p0 - dp; if (a0 > 0.0) aS += a0;
                double a1 = p1 - dp; if (a1 > 0.0) aS += a1;
                double a2 = p2 - dp; if (a2 > 0.0) aS += a2;
                double a3 = p3 - dp; if (a3 > 0.0) aS += a3;
            }
            for (int off = 32; off; off >>= 1) aS += __shfl_down(aS, off, 64);
            if (lane == 0) s_pA[c][wv] = aS;
        }
    }
    __syncthreads();

    // ---------------- Phase 4: 15-segment CDF walk (wave 0) ---------------
    if (wv == 0) {
        double X = 0.0;
        if (lane >= 1 && lane <= NSLOT) {
            if (useAdj) {
                #pragma unroll
                for (int w = 0; w < NW; ++w) X += s_pA[lane - 1][w];
            } else {
                double t = 0.0;
                #pragma unroll
                for (int w = 0; w < NW; ++w) t += s_pR[lane - 1][w];
                X = t * invZ;
            }
        } else if (lane == 0) {
            for (int j = 0; j < head; ++j) {
                double p = s_ht[j] * invZ;
                X += useAdj ? fmax(p - dp, 0.0) : p;
            }
        } else if (lane == NSEG - 1) {
            int tcnt = VOCAB - head - (nvec << 2);
            for (int j = 0; j < tcnt; ++j) {
                double p = s_ht[3 + j] * invZ;
                X += useAdj ? fmax(p - dp, 0.0) : p;
            }
        }
        double sx = X; // inclusive scan over segment index == lane
        for (int off = 1; off < 16; off <<= 1) {
            double vv = __shfl_up(sx, (unsigned)off, 64);
            if (lane >= off) sx += vv;
        }
        double Tot = __shfl(sx, NSEG - 1, 64);
        double T   = (double)usmp[b] * Tot;
        bool crossed = (lane < NSEG) && (sx >= T);
        unsigned long long mk = __ballot(crossed);
        int    cseg = mk ? (int)(__ffsll(mk) - 1) : (NSEG - 1);
        double Pex  = __shfl(sx, cseg, 64) - __shfl(X, cseg, 64);
        if (lane == 0) {
            s_db[0] = Pex; s_db[1] = T;
            s_ib[0] = cseg;
        }
    }
    __syncthreads();

    const double P    = s_db[0];
    const double T    = s_db[1];
    const int    cseg = s_ib[0];

    // ---------------- Phase 5: in-segment scan -> sampled index -----------
    if (cseg >= 1 && cseg <= NSLOT) { // block-uniform branch
        const int  c     = cseg - 1;
        const int  i4    = c * NT + tid;
        const bool valid = i4 < nvec;
        double c0 = 0, c1 = 0, c2 = 0, c3 = 0, tsum = 0;
        if (valid) {
            float4 x = row4[i4]; // L2-hit; expf bit-matches earlier passes
            double p0 = (double)expf(x.x) * invZ;
            double p1 = (double)expf(x.y) * invZ;
            double p2 = (double)expf(x.z) * invZ;
            double p3 = (double)expf(x.w) * invZ;
            double g0 = useAdj ? fmax(p0 - dp, 0.0) : p0;
            double g1 = useAdj ? fmax(p1 - dp, 0.0) : p1;
            double g2 = useAdj ? fmax(p2 - dp, 0.0) : p2;
            double g3 = useAdj ? fmax(p3 - dp, 0.0) : p3;
            c0 = g0; c1 = c0 + g1; c2 = c1 + g2; c3 = c2 + g3;
            tsum = c3;
        }
        // wave inclusive scan of per-thread totals
        double sc = tsum;
        for (int off = 1; off < 64; off <<= 1) {
            double v = __shfl_up(sc, (unsigned)off, 64);
            if (lane >= off) sc += v;
        }
        if (lane == 63) s_w[wv] = sc;
        __syncthreads();
        double woff = 0.0;
        for (int w = 0; w < wv; ++w) woff += s_w[w];
        double base = P + woff + (sc - tsum); // exclusive prefix for this thread
        int bj = -1;
        if (valid) {
            if      (base + c0 >= T) bj = 0;
            else if (base + c1 >= T) bj = 1;
            else if (base + c2 >= T) bj = 2;
            else if (base + c3 >= T) bj = 3;
        }
        unsigned long long mk = __ballot(bj >= 0);
        int L  = mk ? (int)(__ffsll(mk) - 1) : 0;
        int jl = __shfl(bj, L, 64); // first crossing lane's element offset
        __shared__ int s_c[NW];
        if (lane == 0)
            s_c[wv] = mk ? (head + 4 * (c * NT + wv * 64 + L) + jl) : 0x7FFFFFFF;
        __syncthreads();
        if (tid == 0) {
            int best = 0x7FFFFFFF;
            for (int w = 0; w < NW; ++w) best = min(best, s_c[w]);
            int smp;
            if (best == 0x7FFFFFFF) { // rounding guard: segment end
                int endv = c * NT + NT; if (endv > nvec) endv = nvec;
                smp = head + 4 * endv - 1;
            } else {
                smp = best;
            }
            out[NBATCH * KD + NBATCH + b] = smp;
        }
    } else if (tid == 0) { // head (cseg==0) or tail segment: <=3 elems, serial
        int smp = -1;
        if (cseg == 0) {
            double cum = P;
            for (int j = 0; j < head; ++j) {
                double p = s_ht[j] * invZ;
                double g = useAdj ? fmax(p - dp, 0.0) : p;
                cum += g;
                if (cum >= T) { smp = j; break; }
            }
            if (smp < 0) smp = (head > 0) ? head - 1 : 0;
        } else {
            int ts   = head + (nvec << 2);
            int tcnt = VOCAB - ts;
            double cum = P;
            for (int j = 0; j < tcnt; ++j) {
                double p = s_ht[3 + j] * invZ;
                double g = useAdj ? fmax(p - dp, 0.0) : p;
                cum += g;
                if (cum >= T) { smp = ts + j; break; }
            }
            if (smp < 0) smp = VOCAB - 1;
        }
        out[NBATCH * KD + NBATCH + b] = smp;
    }
}

extern "C" void kernel_launch(void* const* d_in, const int* in_sizes, int n_in,
                              void* d_out, int out_size, void* d_ws, size_t ws_size,
                              hipStream_t stream) {
    const int*   dtok   = (const int*)d_in[0];
    const float* dlp    = (const float*)d_in[1];
    const float* logits = (const float*)d_in[2];
    const float* rnd    = (const float*)d_in[3];
    const float* usmp   = (const float*)d_in[4];
    int*         out    = (int*)d_out;
    (void)in_sizes; (void)n_in; (void)out_size; (void)d_ws; (void)ws_size;
    spec_decode_kernel<<<dim3(NBATCH), dim3(NT), 0, stream>>>(
        dtok, dlp, logits, rnd, usmp, out);
}